// Round 10
// baseline (161.558 us; speedup 1.0000x reference)
//
#include <hip/hip_runtime.h>

// MyConv: masked 3x3 conv, B=8, Cin=Cout=128, H=W=128, pad=1, stride=1.
// v13 = v12 (fused, row-dedup, in-place ring) + w-split for occupancy:
// each block does 2 h-rows x 64 w-cols (grid 1024 = 8b x 64h0 x 2whalf).
// v12 counters: conv 52us, ALL pipes <30%, Occ 16.5% (2 blocks/CU) ->
// barrier-interval latency with too few resident blocks. Unlike v6 (which
// doubled staging per output and regressed), the w-split halves per-block
// staging too: slab = 66 slots (64 w + 2 halo), total conversion +3% only,
// per-thread stage depth 16->8 loads, LDS 17KB -> 4 blocks/CU, VGPR<=128
// (acc[4][4]). Swizzle/read scheme v5-verbatim (invariant mod 16 slots);
// slot->ci perm ci=4s+lc matches setup_wp. Kill-switch: conv>=52 => the
// occupancy lever is dead under both staging regimes.

typedef __bf16 bf16x8 __attribute__((ext_vector_type(8)));
typedef unsigned short u16x8 __attribute__((ext_vector_type(8)));
typedef float f32x4 __attribute__((ext_vector_type(4)));

__device__ __forceinline__ unsigned short f2bf(float f) {
    unsigned int u = __float_as_uint(f);
    u += 0x7fffu + ((u >> 16) & 1u);   // round-to-nearest-even
    return (unsigned short)(u >> 16);
}

// ---- weight pack: wp[kh][cb][kw][m][ci32], k-slot perm ci=4*(j&7)+(j>>3) ----
__global__ void setup_wp(const float* __restrict__ wgt, unsigned short* __restrict__ wpp) {
    const int e    = blockIdx.x * 256 + threadIdx.x;   // 576*256 = 147456
    const int j    = e & 31;
    const int m    = (e >> 5) & 127;
    const int r    = e >> 12;
    const int kw   = r - (r / 3) * 3;
    const int cbkh = r / 3;
    const int cb   = cbkh & 3;
    const int kh   = cbkh >> 2;
    const int ci   = 4 * (j & 7) + (j >> 3);
    wpp[e] = f2bf(wgt[((m * 128 + cb * 32 + ci) * 3 + kh) * 3 + kw]);
}

#define SLAB 4224   // 66 slots x 64B

// ---- stage one slot (32 ci of one (h, w) site): 8 coalesced fp32 loads +
//      f2bf + ONE ds_write_b128 to the swizzled chunk. ----
__device__ __forceinline__ void stage_slot(const float* __restrict__ x,
                                           unsigned char* slab,
                                           int b, int cb, int h, int w0,
                                           int p, int lc) {
    const int gw    = w0 - 1 + p;                     // global w of slot p
    const bool val  = ((unsigned)h < 128u) & ((unsigned)gw < 128u);
    u16x8 o = {0, 0, 0, 0, 0, 0, 0, 0};
    if (val) {
        const float* xr = x + ((((b * 128 + cb * 32) * 128) + h) << 7) + gw;
        #pragma unroll
        for (int s = 0; s < 8; ++s)                   // ci = cb*32 + 4s + lc
            o[s] = f2bf(xr[(lc << 14) + (s << 16)]);
    }
    *(u16x8*)(slab + p * 64 + ((lc ^ ((p + (p >> 2)) & 3)) << 4)) = o;
}

// ---- stage one padded row (66 slots x 32ci) with 256 threads ----
// wave = chunk lc; lane = slot p (lanes 0,1 also take slots 64,65).
__device__ __forceinline__ void stage1(const float* __restrict__ x,
                                       unsigned char* slab,
                                       int b, int cb, int h, int w0, int t) {
    const int lc = t >> 6;
    const int p  = t & 63;
    stage_slot(x, slab, b, cb, h, w0, p, lc);
    if (p < 2) stage_slot(x, slab, b, cb, h, w0, p + 64, lc);
}

__global__ __launch_bounds__(256, 4)
void myconv13(const float* __restrict__ x,
              const int* __restrict__ mask,
              const unsigned short* __restrict__ wp,
              const float* __restrict__ bias,
              float* __restrict__ out)
{
    __shared__ __align__(16) unsigned char Xs[4 * SLAB];  // 4 row positions
    __shared__ float act[128];

    const int t = threadIdx.x;           // 0..255
    // XCD remap (R7: FETCH -9MB measured): XCD = batch; (h0, whalf) inner.
    const int b     = blockIdx.x & 7;
    const int whalf = (blockIdx.x >> 3) & 1;
    const int h0    = ((blockIdx.x >> 4) & 63) << 1;   // 0..126
    const int w0    = whalf << 6;

    const int lane  = t & 63;
    const int l16   = lane & 15;
    const int q     = lane >> 4;
    const int g     = (t >> 6) & 1;      // wave -> output h row
    const int mhalf = t >> 7;            // wave -> Cout half

    // ---- active map for rows h0,h0+1 x w-cols w0..w0+63 (t = gg*64+wl) ----
    if (t < 128) {
        const int gg = t >> 6;
        const int wl = t & 63;
        const int h  = h0 + gg;
        int any = 0;
        #pragma unroll
        for (int kh = 0; kh < 3; ++kh) {
            int hh = h + kh - 1;
            if ((unsigned)hh < 128u) {
                const int* mrow = mask + (b * 128 + hh) * 128;
                #pragma unroll
                for (int kw = 0; kw < 3; ++kw) {
                    int ww = w0 + wl + kw - 1;
                    if ((unsigned)ww < 128u) any |= mrow[ww];
                }
            }
        }
        act[t] = any ? 1.0f : 0.0f;
    }

    // ---- prologue: stage cb=0's 4 rows into positions 0..3 ----
    #pragma unroll
    for (int y = 0; y < 4; ++y)
        stage1(x, &Xs[y * SLAB], b, 0, h0 - 1 + y, w0, t);

    // B fragment byte offsets (per kw, j-independent swizzle; p = l16+kw+16j,
    // swz(p+16) == swz(p) mod 4 -> slot-swz from l16+kw alone, + j*1024)
    int bb[3];
    #pragma unroll
    for (int kw = 0; kw < 3; ++kw) {
        const int rr   = l16 + kw;
        const int slot = q ^ ((rr + (rr >> 2)) & 3);
        bb[kw] = rr * 64 + (slot << 4);
    }

    const unsigned char* agl = (const unsigned char*)wp + (mhalf * 64 + l16) * 64 + q * 16;

    f32x4 acc[4][4];
    const f32x4 fzero = {0.f, 0.f, 0.f, 0.f};
    #pragma unroll
    for (int i = 0; i < 4; ++i)
        #pragma unroll
        for (int j = 0; j < 4; ++j)
            acc[i][j] = fzero;

    __syncthreads();   // prologue staging + act complete

#define COMPUTE_KH(k)                                                          \
    {                                                                          \
        const unsigned char* ar = agl + ((k) * 4 + cb) * 24576;                \
        const unsigned char* xb = &Xs[((k) + g) * SLAB];                       \
        _Pragma("unroll")                                                      \
        for (int kw = 0; kw < 3; ++kw) {                                       \
            bf16x8 af[4];                                                      \
            _Pragma("unroll")                                                  \
            for (int i = 0; i < 4; ++i)                                        \
                af[i] = *(const bf16x8*)(ar + kw * 8192 + i * 1024);           \
            bf16x8 bfr[4];                                                     \
            _Pragma("unroll")                                                  \
            for (int j = 0; j < 4; ++j)                                        \
                bfr[j] = *(const bf16x8*)(xb + bb[kw] + j * 1024);             \
            _Pragma("unroll")                                                  \
            for (int i = 0; i < 4; ++i)                                        \
                _Pragma("unroll")                                              \
                for (int j = 0; j < 4; ++j)                                    \
                    acc[i][j] = __builtin_amdgcn_mfma_f32_16x16x32_bf16(       \
                        af[i], bfr[j], acc[i][j], 0, 0, 0);                    \
        }                                                                      \
    }

    for (int cb = 0; cb < 4; ++cb) {
        // I0: stage cb.s2,s3 (freed by prev cb's kh1/kh2); kh0 reads 0,1.
        if (cb > 0) {
            stage1(x, &Xs[2 * SLAB], b, cb, h0 + 1, w0, t);
            stage1(x, &Xs[3 * SLAB], b, cb, h0 + 2, w0, t);
        }
        COMPUTE_KH(0);
        __syncthreads();

        // I1: stage (cb+1).s0 into pos0 (freed by kh0); kh1 reads 1,2.
        if (cb < 3) stage1(x, &Xs[0 * SLAB], b, cb + 1, h0 - 1, w0, t);
        COMPUTE_KH(1);
        __syncthreads();

        // I2: stage (cb+1).s1 into pos1 (freed by kh1); kh2 reads 2,3.
        if (cb < 3) stage1(x, &Xs[1 * SLAB], b, cb + 1, h0 + 0, w0, t);
        COMPUTE_KH(2);
        __syncthreads();
    }
#undef COMPUTE_KH

    // ---- epilogue: (acc + bias) * active ----
    #pragma unroll
    for (int i = 0; i < 4; ++i) {
        const int m0 = mhalf * 64 + (i << 4) + (q << 2);
        const f32x4 bv = *(const f32x4*)(bias + m0);
        #pragma unroll
        for (int j = 0; j < 4; ++j) {
            const int wl = (j << 4) + l16;
            const float a = act[(g << 6) + wl];
            float* base = out + (((b << 7) + m0) << 14) + ((h0 + g) << 7) + w0 + wl;
            #pragma unroll
            for (int rg = 0; rg < 4; ++rg)
                base[rg << 14] = (acc[i][j][rg] + bv[rg]) * a;
        }
    }
}

// ---------------- fallback (used only if ws too small) ----------------
#define LDAF 40
__global__ __launch_bounds__(256, 2)
void myconv_fb(const float* __restrict__ x,
               const int* __restrict__ mask,
               const float* __restrict__ wgt,
               const float* __restrict__ bias,
               float* __restrict__ out)
{
    __shared__ unsigned short As[128 * LDAF];
    __shared__ unsigned short Bs[128 * LDAF];
    __shared__ float act[128];

    const int t   = threadIdx.x;
    const int blk = blockIdx.x;
    const int b   = blk >> 7;
    const int h   = blk & 127;

    if (t < 128) {
        int any = 0;
        #pragma unroll
        for (int kh = 0; kh < 3; ++kh) {
            int hh = h + kh - 1;
            if ((unsigned)hh < 128u) {
                const int* mrow = mask + (b * 128 + hh) * 128;
                #pragma unroll
                for (int kw = 0; kw < 3; ++kw) {
                    int ww = t + kw - 1;
                    if ((unsigned)ww < 128u) any |= mrow[ww];
                }
            }
        }
        act[t] = any ? 1.0f : 0.0f;
    }

    const int lane = t & 63;
    const int l16  = lane & 15;
    const int half = lane >> 4;
    const int wv   = t >> 6;
    const int wm   = (wv >> 1) << 6;
    const int wn   = (wv & 1) << 6;

    f32x4 acc[4][4];
    const f32x4 fzero = {0.f, 0.f, 0.f, 0.f};
    #pragma unroll
    for (int i = 0; i < 4; ++i)
        #pragma unroll
        for (int j = 0; j < 4; ++j)
            acc[i][j] = fzero;

    const int am  = t >> 3;
    const int ac4 = (t & 7) << 2;
    const int n     = t & 127;
    const int khalf = __builtin_amdgcn_readfirstlane(t >> 7);
    const int xb    = b << 21;

    for (int kt = 0; kt < 36; ++kt) {
        __syncthreads();
        #pragma unroll
        for (int jj = 0; jj < 4; ++jj) {
            const int m = am + (jj << 5);
            const float4 v = *(const float4*)(wgt + m * 1152 + kt * 32 + ac4);
            unsigned short* dst = &As[m * LDAF + ac4];
            dst[0] = f2bf(v.x); dst[1] = f2bf(v.y); dst[2] = f2bf(v.z); dst[3] = f2bf(v.w);
        }
        u16x8 bv0, bv1;
        #pragma unroll
        for (int s = 0; s < 16; ++s) {
            const int k  = kt * 32 + khalf * 16 + s;
            const int ci = (k * 7282) >> 16;
            const int r  = k - ci * 9;
            const int kh = (r >= 3) + (r >= 6);
            const int kw = r - kh * 3;
            const int hh = h + kh - 1;
            float v = 0.f;
            if ((unsigned)hh < 128u) {
                const int ww = n + kw - 1;
                if ((unsigned)ww < 128u)
                    v = x[xb + (ci << 14) + (hh << 7) + ww];
            }
            if (s < 8) bv0[s] = f2bf(v); else bv1[s - 8] = f2bf(v);
        }
        *(u16x8*)&Bs[n * LDAF + khalf * 16]     = bv0;
        *(u16x8*)&Bs[n * LDAF + khalf * 16 + 8] = bv1;

        __syncthreads();

        bf16x8 af[4], bfr[4];
        #pragma unroll
        for (int i = 0; i < 4; ++i)
            af[i] = *(const bf16x8*)&As[(wm + (i << 4) + l16) * LDAF + (half << 3)];
        #pragma unroll
        for (int j = 0; j < 4; ++j)
            bfr[j] = *(const bf16x8*)&Bs[(wn + (j << 4) + l16) * LDAF + (half << 3)];
        #pragma unroll
        for (int i = 0; i < 4; ++i)
            #pragma unroll
            for (int j = 0; j < 4; ++j)
                acc[i][j] = __builtin_amdgcn_mfma_f32_16x16x32_bf16(af[i], bfr[j], acc[i][j], 0, 0, 0);
    }

    #pragma unroll
    for (int i = 0; i < 4; ++i) {
        #pragma unroll
        for (int j = 0; j < 4; ++j) {
            const int ncol = wn + (j << 4) + l16;
            const float a  = act[ncol];
            #pragma unroll
            for (int rg = 0; rg < 4; ++rg) {
                const int m = wm + (i << 4) + (half << 2) + rg;
                out[(((b << 7) + m) << 14) + (h << 7) + ncol] =
                    (acc[i][j][rg] + bias[m]) * a;
            }
        }
    }
}

extern "C" void kernel_launch(void* const* d_in, const int* in_sizes, int n_in,
                              void* d_out, int out_size, void* d_ws, size_t ws_size,
                              hipStream_t stream) {
    const float* x    = (const float*)d_in[0];
    const int*   mask = (const int*)d_in[1];
    const float* wgt  = (const float*)d_in[2];
    const float* bias = (const float*)d_in[3];
    float* out        = (float*)d_out;

    const size_t WP_ELEMS = 36ull * 128 * 32;   // 147,456 bf16
    if (ws_size >= WP_ELEMS * 2) {
        unsigned short* wpw = (unsigned short*)d_ws;
        setup_wp<<<dim3(576), dim3(256), 0, stream>>>(wgt, wpw);
        myconv13<<<dim3(1024), dim3(256), 0, stream>>>(x, mask, wpw, bias, out);
    } else {
        myconv_fb<<<dim3(1024), dim3(256), 0, stream>>>(x, mask, wgt, bias, out);
    }
}